// Round 13
// baseline (134.567 us; speedup 1.0000x reference)
//
#include <hip/hip_runtime.h>
#include <stdint.h>

#define NB    1024
#define IL    4096
#define NOUT  4096
#define FI    128
#define BTILE 8
#define OSPLIT 4
#define OTILE (NOUT / OSPLIT)        // 1024 outputs per block
#define SLAB_DW (IL * (BTILE / 2))   // 16384 dwords = 64KB per batch-group slab
#define SLAB_BLOCKS ((NB / BTILE) * IL / 256)   // 2048
#define SORT_BLOCKS (NOUT / 4)                  // 1024 (wave per row)

__device__ __forceinline__ uint32_t rne_bf16_hi(float x) {
  uint32_t u = __float_as_uint(x);
  u += 0x7FFFu + ((u >> 16) & 1u);
  return u & 0xFFFF0000u;
}

// merged pre-pass: slab build + comb-sorted pack (unchanged)
__global__ __launch_bounds__(256)
void prep_kernel(const float* __restrict__ in, uint32_t* __restrict__ slab,
                 const int* __restrict__ idx, const float* __restrict__ w,
                 uint32_t* __restrict__ pack) {
  const int bid = blockIdx.x;
  if (bid < SLAB_BLOCKS) {
    int t = bid * 256 + threadIdx.x;
    int g = t >> 12;
    int i = t & (IL - 1);
    const float* base = in + (size_t)g * (8 * IL) + i;
    uint4 v;
    v.x = rne_bf16_hi(base[1 * IL]) | (rne_bf16_hi(base[0 * IL]) >> 16);
    v.y = rne_bf16_hi(base[3 * IL]) | (rne_bf16_hi(base[2 * IL]) >> 16);
    v.z = rne_bf16_hi(base[5 * IL]) | (rne_bf16_hi(base[4 * IL]) >> 16);
    v.w = rne_bf16_hi(base[7 * IL]) | (rne_bf16_hi(base[6 * IL]) >> 16);
    reinterpret_cast<uint4*>(slab)[t] = v;
  } else {
    const int o = (bid - SLAB_BLOCKS) * 4 + (threadIdx.x >> 6);
    const unsigned lane = threadIdx.x & 63u;
    const uint32_t r = (uint32_t)(o & 7);
    const int*   irow = idx + (size_t)o * FI;
    const float* wrow = w   + (size_t)o * FI;
    uint32_t* prow = pack + (size_t)o * FI;

    uint32_t i0 = (uint32_t)irow[lane], i1 = (uint32_t)irow[64 + lane];
    uint32_t w0 = rne_bf16_hi(wrow[lane]), w1 = rne_bf16_hi(wrow[64 + lane]);
    uint32_t k0 = i0 & 7u, k1 = i1 & 7u;
    const uint64_t lt = (1ull << lane) - 1ull;

    uint32_t rank0 = 0, rank1 = 0;
    uint64_t cntp = 0;
    #pragma unroll
    for (int g = 0; g < 8; ++g) {
      uint64_t b0 = __ballot(k0 == (uint32_t)g);
      uint64_t b1 = __ballot(k1 == (uint32_t)g);
      uint32_t c0 = (uint32_t)__popcll(b0);
      if (k0 == (uint32_t)g) rank0 = (uint32_t)__popcll(b0 & lt);
      if (k1 == (uint32_t)g) rank1 = c0 + (uint32_t)__popcll(b1 & lt);
      cntp |= (uint64_t)(c0 + (uint32_t)__popcll(b1)) << (8 * g);
    }
    uint64_t ov0 = __ballot(rank0 >= 16u);
    uint64_t ov1 = __ballot(rank1 >= 16u);
    uint32_t ofr0 = (uint32_t)__popcll(ov0 & lt);
    uint32_t ofr1 = (uint32_t)__popcll(ov0) + (uint32_t)__popcll(ov1 & lt);

    auto place = [&](uint32_t k, uint32_t rank, uint32_t ofr) -> uint32_t {
      if (rank < 16u) return ((k - r) & 7u) + 8u * rank;
      uint32_t cum = 0, p = 0;
      bool done = false;
      #pragma unroll
      for (int lc = 0; lc < 8; ++lc) {
        uint32_t gl = ((uint32_t)lc + r) & 7u;
        uint32_t c  = (uint32_t)((cntp >> (8 * gl)) & 0xFFu);
        uint32_t u  = c < 16u ? c : 16u;
        uint32_t lcnt = 16u - u;
        if (!done && ofr < cum + lcnt) { p = (uint32_t)lc + 8u * (u + ofr - cum); done = true; }
        cum += lcnt;
      }
      return p;
    };
    prow[place(k0, rank0, ofr0)] = w0 | ((i0 << 4) & 0xFFFFu);
    prow[place(k1, rank1, ofr1)] = w1 | ((i1 << 4) & 0xFFFFu);
  }
}

// shared staging: linear 64KB DMA global->LDS
__device__ __forceinline__ void stage_slab(const uint32_t* src, uint32_t* lds, int tid) {
  #pragma unroll
  for (int r = 0; r < 4; ++r) {
    int e = (r * 1024 + tid) * 4;
    __builtin_amdgcn_global_load_lds(
        (const __attribute__((address_space(1))) uint32_t*)(src + e),
        (__attribute__((address_space(3))) uint32_t*)(lds + e),
        16, 0, 0);
  }
}

#define FMA8(PV, G) {                                             \
    float wv = __uint_as_float((PV) & 0xFFFF0000u);               \
    acc[0] = fmaf(wv, __uint_as_float((G).x << 16),         acc[0]);\
    acc[1] = fmaf(wv, __uint_as_float((G).x & 0xFFFF0000u), acc[1]);\
    acc[2] = fmaf(wv, __uint_as_float((G).y << 16),         acc[2]);\
    acc[3] = fmaf(wv, __uint_as_float((G).y & 0xFFFF0000u), acc[3]);\
    acc[4] = fmaf(wv, __uint_as_float((G).z << 16),         acc[4]);\
    acc[5] = fmaf(wv, __uint_as_float((G).z & 0xFFFF0000u), acc[5]);\
    acc[6] = fmaf(wv, __uint_as_float((G).w << 16),         acc[6]);\
    acc[7] = fmaf(wv, __uint_as_float((G).w & 0xFFFF0000u), acc[7]);}

// v0 — real kernel (identical to R12), writes d_out
__global__ __launch_bounds__(1024)
void lincond_kernel(const uint32_t* __restrict__ slab,
                    const uint32_t* __restrict__ pack,
                    const float* __restrict__ bias,
                    float* __restrict__ out) {
  __shared__ uint32_t lds[SLAB_DW];
  const int bid   = blockIdx.x;
  const int b0    = (bid >> 2) * BTILE;
  const int obase = (bid & 3) * OTILE;
  const int tid   = threadIdx.x;
  stage_slab(slab + (size_t)(b0 >> 3) * SLAB_DW, lds, tid);
  __syncthreads();

  const int o = obase + tid;
  const char* ldsb = reinterpret_cast<const char*>(lds);
  float acc[8] = {0.f,0.f,0.f,0.f,0.f,0.f,0.f,0.f};
  const uint4* pw = reinterpret_cast<const uint4*>(pack) + (size_t)o * (FI / 4);

  #pragma unroll 2
  for (int j = 0; j < 8; ++j) {
    uint4 pq[4];
    #pragma unroll
    for (int q = 0; q < 4; ++q) pq[q] = pw[j * 4 + q];
    uint32_t pvw[16];
    #pragma unroll
    for (int q = 0; q < 4; ++q) {
      pvw[q * 4 + 0] = pq[q].x; pvw[q * 4 + 1] = pq[q].y;
      pvw[q * 4 + 2] = pq[q].z; pvw[q * 4 + 3] = pq[q].w;
    }
    #pragma unroll
    for (int h = 0; h < 2; ++h) {
      uint4 g[8];
      #pragma unroll
      for (int c = 0; c < 8; ++c)
        g[c] = *reinterpret_cast<const uint4*>(ldsb + (pvw[h * 8 + c] & 0xFFFFu));
      #pragma unroll
      for (int c = 0; c < 8; ++c) FMA8(pvw[h * 8 + c], g[c])
    }
  }

  const float bv = bias[o];
  #pragma unroll
  for (int k = 0; k < 8; ++k)
    out[(size_t)(b0 + k) * NOUT + o] = acc[k] + bv;
}

// DIAGNOSTIC: contiguous per-wave offsets (0 bank conflicts by construction),
// real ds_read_b128 + full FMA chain. No d_out writes; acc sunk once at end.
__global__ __launch_bounds__(1024)
void lincond_seqds(const uint32_t* __restrict__ slab,
                   const uint32_t* __restrict__ pack,
                   const float* __restrict__ bias,
                   float* __restrict__ out) {
  __shared__ uint32_t lds[SLAB_DW];
  const int bid = blockIdx.x;
  const int b0  = (bid >> 2) * BTILE;
  const int tid = threadIdx.x;
  stage_slab(slab + (size_t)(b0 >> 3) * SLAB_DW, lds, tid);
  __syncthreads();

  const int o = ((bid & 3) * OTILE) + tid;
  const char* ldsb = reinterpret_cast<const char*>(lds);
  float acc[8] = {0.f,0.f,0.f,0.f,0.f,0.f,0.f,0.f};
  const uint4* pw = reinterpret_cast<const uint4*>(pack) + (size_t)o * (FI / 4);

  #pragma unroll 2
  for (int j = 0; j < 8; ++j) {
    uint4 pq[4];
    #pragma unroll
    for (int q = 0; q < 4; ++q) pq[q] = pw[j * 4 + q];
    uint32_t pvw[16];
    #pragma unroll
    for (int q = 0; q < 4; ++q) {
      pvw[q * 4 + 0] = pq[q].x; pvw[q * 4 + 1] = pq[q].y;
      pvw[q * 4 + 2] = pq[q].z; pvw[q * 4 + 3] = pq[q].w;
    }
    #pragma unroll
    for (int h = 0; h < 2; ++h) {
      uint4 g[8];
      #pragma unroll
      for (int c = 0; c < 8; ++c) {
        int step = j * 16 + h * 8 + c;
        uint32_t off = (uint32_t)(((step * 64 + (tid & 63)) & (IL - 1)) << 4);  // wave reads 1KB contiguous
        g[c] = *reinterpret_cast<const uint4*>(ldsb + off);
      }
      #pragma unroll
      for (int c = 0; c < 8; ++c) FMA8(pvw[h * 8 + c], g[c])
    }
  }
  asm volatile("" :: "v"(acc[0]), "v"(acc[1]), "v"(acc[2]), "v"(acc[3]),
                     "v"(acc[4]), "v"(acc[5]), "v"(acc[6]), "v"(acc[7]));
}

// DIAGNOSTIC: no LDS gathers at all — fabricated data, full FMA/unpack chain.
__global__ __launch_bounds__(1024)
void lincond_nods(const uint32_t* __restrict__ slab,
                  const uint32_t* __restrict__ pack,
                  const float* __restrict__ bias,
                  float* __restrict__ out) {
  __shared__ uint32_t lds[SLAB_DW];
  const int bid = blockIdx.x;
  const int b0  = (bid >> 2) * BTILE;
  const int tid = threadIdx.x;
  stage_slab(slab + (size_t)(b0 >> 3) * SLAB_DW, lds, tid);
  __syncthreads();

  const int o = ((bid & 3) * OTILE) + tid;
  float acc[8] = {0.f,0.f,0.f,0.f,0.f,0.f,0.f,0.f};
  const uint4* pw = reinterpret_cast<const uint4*>(pack) + (size_t)o * (FI / 4);

  #pragma unroll 2
  for (int j = 0; j < 8; ++j) {
    uint4 pq[4];
    #pragma unroll
    for (int q = 0; q < 4; ++q) pq[q] = pw[j * 4 + q];
    uint32_t pvw[16];
    #pragma unroll
    for (int q = 0; q < 4; ++q) {
      pvw[q * 4 + 0] = pq[q].x; pvw[q * 4 + 1] = pq[q].y;
      pvw[q * 4 + 2] = pq[q].z; pvw[q * 4 + 3] = pq[q].w;
    }
    #pragma unroll
    for (int h = 0; h < 2; ++h) {
      #pragma unroll
      for (int c = 0; c < 8; ++c) {
        uint32_t pv = pvw[h * 8 + c];
        uint4 g;  // fabricated in-register (2 VALU), replaces the ds_read
        g.x = pv; g.y = pv << 1; g.z = pv >> 1; g.w = pv ^ 0xFFFFu;
        FMA8(pv, g)
      }
    }
  }
  asm volatile("" :: "v"(acc[0]), "v"(acc[1]), "v"(acc[2]), "v"(acc[3]),
                     "v"(acc[4]), "v"(acc[5]), "v"(acc[6]), "v"(acc[7]));
}

// fallback (no workspace): naive but correct
__global__ __launch_bounds__(256)
void lincond_raw(const float* __restrict__ input, const float* __restrict__ wgt,
                 const float* __restrict__ bias, const int* __restrict__ idxs,
                 float* __restrict__ out) {
  int t = blockIdx.x * 256 + threadIdx.x;
  int b = t >> 12, o = t & (NOUT - 1);
  const float* irow = input + (size_t)b * IL;
  const int*   ix   = idxs + (size_t)o * FI;
  const float* wr   = wgt  + (size_t)o * FI;
  float acc = bias[o];
  for (int f = 0; f < FI; ++f) acc += wr[f] * irow[ix[f]];
  out[t] = acc;
}

extern "C" void kernel_launch(void* const* d_in, const int* in_sizes, int n_in,
                              void* d_out, int out_size, void* d_ws, size_t ws_size,
                              hipStream_t stream) {
  const float* input  = (const float*)d_in[0];
  const float* weight = (const float*)d_in[1];
  const float* bias   = (const float*)d_in[2];
  const int*   idxs   = (const int*)d_in[3];
  float*       out    = (float*)d_out;

  const size_t pack_bytes = (size_t)NOUT * FI * sizeof(uint32_t);              // 2 MB
  const size_t slab_bytes = (size_t)(NB / BTILE) * SLAB_DW * sizeof(uint32_t); // 8 MB
  const int grid = (NB / BTILE) * OSPLIT;                                      // 512

  if (ws_size >= pack_bytes + slab_bytes) {
    uint32_t* pack = (uint32_t*)d_ws;
    uint32_t* slab = (uint32_t*)((char*)d_ws + pack_bytes);
    prep_kernel<<<SLAB_BLOCKS + SORT_BLOCKS, 256, 0, stream>>>(input, slab, idxs, weight, pack);
    lincond_kernel<<<grid, 1024, 0, stream>>>(slab, pack, bias, out);  // real
    lincond_seqds <<<grid, 1024, 0, stream>>>(slab, pack, bias, out);  // 0-conflict DS
    lincond_nods  <<<grid, 1024, 0, stream>>>(slab, pack, bias, out);  // no-DS
  } else {
    lincond_raw<<<(NB * NOUT) / 256, 256, 0, stream>>>(input, weight, bias, idxs, out);
  }
}

// Round 14
// 52.942 us; speedup vs baseline: 2.5418x; 2.5418x over previous
//
#include <hip/hip_runtime.h>
#include <hip/hip_fp16.h>
#include <stdint.h>

#define NB    1024
#define IL    4096
#define NOUT  4096
#define FI    128
#define BTILE 8
#define OSPLIT 4
#define OTILE (NOUT / OSPLIT)        // 1024 outputs per block
#define SLAB_DW (IL * (BTILE / 2))   // 16384 dwords = 64KB per batch-group slab
#define SLAB_BLOCKS ((NB / BTILE) * IL / 256)   // 2048
#define SORT_BLOCKS (NOUT / 4)                  // 1024 (wave per row)

typedef _Float16 h2v __attribute__((ext_vector_type(2)));
__device__ __forceinline__ h2v as_h2(uint32_t u){ union{uint32_t u; h2v h;} c; c.u=u; return c.h; }
#if __has_builtin(__builtin_amdgcn_fdot2)
__device__ __forceinline__ float fdot2(h2v a, h2v b, float c){ return __builtin_amdgcn_fdot2(a,b,c,false); }
#else
__device__ __forceinline__ float fdot2(h2v a, h2v b, float c){ return c + (float)a[0]*(float)b[0] + (float)a[1]*(float)b[1]; }
#endif

__device__ __forceinline__ uint32_t f16bits(float x) {
  return (uint32_t)__half_as_ushort(__float2half(x));   // RNE f32->f16
}

// ---------------- merged pre-pass (one launch) ----------------
// bid <  SLAB_BLOCKS : f16 slab  row i = uint4 = 8 batches f16 (dword d: batch 2d lo16, 2d+1 hi16)
// bid >= SLAB_BLOCKS : comb-sorted PAIRED pack: per o, 64 uint2 entries
//   {addrs = a(f1)<<16 | a(f2),  weights = h16(w1) | h16(w2)<<16}
//   where (f1,f2) = comb-sorted positions (2t, 2t+1).  Comb: entry with bank
//   group g=idx&7, rank k<16 -> position ((g-(o&7))&7)+8k; overflow fills leftovers.
__global__ __launch_bounds__(256)
void prep_kernel(const float* __restrict__ in, uint32_t* __restrict__ slab,
                 const int* __restrict__ idx, const float* __restrict__ w,
                 uint2* __restrict__ pack2) {
  __shared__ uint32_t sbuf[4][FI];   // sorted-entry scratch, one row per wave
  const int bid = blockIdx.x;
  if (bid < SLAB_BLOCKS) {
    int t = bid * 256 + threadIdx.x;
    int g = t >> 12;
    int i = t & (IL - 1);
    const float* base = in + (size_t)g * (8 * IL) + i;
    uint4 v;
    v.x = (f16bits(base[1 * IL]) << 16) | f16bits(base[0 * IL]);
    v.y = (f16bits(base[3 * IL]) << 16) | f16bits(base[2 * IL]);
    v.z = (f16bits(base[5 * IL]) << 16) | f16bits(base[4 * IL]);
    v.w = (f16bits(base[7 * IL]) << 16) | f16bits(base[6 * IL]);
    reinterpret_cast<uint4*>(slab)[t] = v;
  } else {
    const int wv = threadIdx.x >> 6;
    const int o = (bid - SLAB_BLOCKS) * 4 + wv;
    const unsigned lane = threadIdx.x & 63u;
    const uint32_t r = (uint32_t)(o & 7);
    const int*   irow = idx + (size_t)o * FI;
    const float* wrow = w   + (size_t)o * FI;

    uint32_t i0 = (uint32_t)irow[lane], i1 = (uint32_t)irow[64 + lane];
    uint32_t e0 = (f16bits(wrow[lane])      << 16) | ((i0 << 4) & 0xFFFFu);
    uint32_t e1 = (f16bits(wrow[64 + lane]) << 16) | ((i1 << 4) & 0xFFFFu);
    uint32_t k0 = i0 & 7u, k1 = i1 & 7u;
    const uint64_t lt = (1ull << lane) - 1ull;

    uint32_t rank0 = 0, rank1 = 0;
    uint64_t cntp = 0;
    #pragma unroll
    for (int g = 0; g < 8; ++g) {
      uint64_t b0 = __ballot(k0 == (uint32_t)g);
      uint64_t b1 = __ballot(k1 == (uint32_t)g);
      uint32_t c0 = (uint32_t)__popcll(b0);
      if (k0 == (uint32_t)g) rank0 = (uint32_t)__popcll(b0 & lt);
      if (k1 == (uint32_t)g) rank1 = c0 + (uint32_t)__popcll(b1 & lt);
      cntp |= (uint64_t)(c0 + (uint32_t)__popcll(b1)) << (8 * g);
    }
    uint64_t ov0 = __ballot(rank0 >= 16u);
    uint64_t ov1 = __ballot(rank1 >= 16u);
    uint32_t ofr0 = (uint32_t)__popcll(ov0 & lt);
    uint32_t ofr1 = (uint32_t)__popcll(ov0) + (uint32_t)__popcll(ov1 & lt);

    auto place = [&](uint32_t k, uint32_t rank, uint32_t ofr) -> uint32_t {
      if (rank < 16u) return ((k - r) & 7u) + 8u * rank;
      uint32_t cum = 0, p = 0;
      bool done = false;
      #pragma unroll
      for (int lc = 0; lc < 8; ++lc) {
        uint32_t gl = ((uint32_t)lc + r) & 7u;
        uint32_t c  = (uint32_t)((cntp >> (8 * gl)) & 0xFFu);
        uint32_t u  = c < 16u ? c : 16u;
        uint32_t lcnt = 16u - u;
        if (!done && ofr < cum + lcnt) { p = (uint32_t)lc + 8u * (u + ofr - cum); done = true; }
        cum += lcnt;
      }
      return p;
    };
    sbuf[wv][place(k0, rank0, ofr0)] = e0;
    sbuf[wv][place(k1, rank1, ofr1)] = e1;
    __syncthreads();   // uniform branch within block: safe

    uint32_t s0 = sbuf[wv][2 * lane], s1 = sbuf[wv][2 * lane + 1];
    uint2 pe;
    pe.x = ((s0 & 0xFFFFu) << 16) | (s1 & 0xFFFFu);        // addr(f1) hi | addr(f2) lo
    pe.y = (s1 & 0xFFFF0000u) | (s0 >> 16);                // w2 hi | w1 lo
    pack2[(size_t)o * 64 + lane] = pe;
  }
}

// shared staging: linear 64KB DMA global->LDS
__device__ __forceinline__ void stage_slab(const uint32_t* src, uint32_t* lds, int tid) {
  #pragma unroll
  for (int r = 0; r < 4; ++r) {
    int e = (r * 1024 + tid) * 4;
    __builtin_amdgcn_global_load_lds(
        (const __attribute__((address_space(1))) uint32_t*)(src + e),
        (__attribute__((address_space(3))) uint32_t*)(lds + e),
        16, 0, 0);
  }
}

// main kernel: DMA staging + paired-gather dot2 loop.
// Per pair-entry: 2 ds_read_b128 + 8 v_perm + 8 v_dot2_f32_f16 = 16 MACs.
__global__ __launch_bounds__(1024)
void lincond_kernel(const uint32_t* __restrict__ slab,
                    const uint2* __restrict__ pack2,
                    const float* __restrict__ bias,
                    float* __restrict__ out) {
  __shared__ uint32_t lds[SLAB_DW];
  const int bid   = blockIdx.x;
  const int b0    = (bid >> 2) * BTILE;
  const int obase = (bid & 3) * OTILE;
  const int tid   = threadIdx.x;
  stage_slab(slab + (size_t)(b0 >> 3) * SLAB_DW, lds, tid);
  __syncthreads();

  const int o = obase + tid;
  const char* ldsb = reinterpret_cast<const char*>(lds);
  float acc[8] = {0.f,0.f,0.f,0.f,0.f,0.f,0.f,0.f};
  const uint4* pw4 = reinterpret_cast<const uint4*>(pack2) + (size_t)o * 32;

// one batch-dword pair: u1 = row(f1) dword, u2 = row(f2) dword, batches k0(lo16),k1(hi16)
#define DOT2P(U1, U2, WT, K0, K1) {                                             \
    acc[K0] = fdot2(as_h2(__builtin_amdgcn_perm((U2), (U1), 0x05040100u)),      \
                    as_h2(WT), acc[K0]);                                        \
    acc[K1] = fdot2(as_h2(__builtin_amdgcn_perm((U2), (U1), 0x07060302u)),      \
                    as_h2(WT), acc[K1]);}

#define ENTRY(AD, WT) {                                                         \
    uint32_t a1 = (AD) >> 16, a2 = (AD) & 0xFFFFu;                              \
    uint4 g1 = *reinterpret_cast<const uint4*>(ldsb + a1);                      \
    uint4 g2 = *reinterpret_cast<const uint4*>(ldsb + a2);                      \
    DOT2P(g1.x, g2.x, WT, 0, 1)                                                 \
    DOT2P(g1.y, g2.y, WT, 2, 3)                                                 \
    DOT2P(g1.z, g2.z, WT, 4, 5)                                                 \
    DOT2P(g1.w, g2.w, WT, 6, 7)}

  #pragma unroll 2
  for (int j = 0; j < 8; ++j) {
    uint4 pq[4];
    #pragma unroll
    for (int q = 0; q < 4; ++q) pq[q] = pw4[j * 4 + q];
    #pragma unroll
    for (int q = 0; q < 4; ++q) {
      ENTRY(pq[q].x, pq[q].y)
      ENTRY(pq[q].z, pq[q].w)
    }
  }

  const float bv = bias[o];
  #pragma unroll
  for (int k = 0; k < 8; ++k)
    out[(size_t)(b0 + k) * NOUT + o] = acc[k] + bv;
}

// fallback (no workspace): naive but correct
__global__ __launch_bounds__(256)
void lincond_raw(const float* __restrict__ input, const float* __restrict__ wgt,
                 const float* __restrict__ bias, const int* __restrict__ idxs,
                 float* __restrict__ out) {
  int t = blockIdx.x * 256 + threadIdx.x;
  int b = t >> 12, o = t & (NOUT - 1);
  const float* irow = input + (size_t)b * IL;
  const int*   ix   = idxs + (size_t)o * FI;
  const float* wr   = wgt  + (size_t)o * FI;
  float acc = bias[o];
  for (int f = 0; f < FI; ++f) acc += wr[f] * irow[ix[f]];
  out[t] = acc;
}

extern "C" void kernel_launch(void* const* d_in, const int* in_sizes, int n_in,
                              void* d_out, int out_size, void* d_ws, size_t ws_size,
                              hipStream_t stream) {
  const float* input  = (const float*)d_in[0];
  const float* weight = (const float*)d_in[1];
  const float* bias   = (const float*)d_in[2];
  const int*   idxs   = (const int*)d_in[3];
  float*       out    = (float*)d_out;

  const size_t pack_bytes = (size_t)NOUT * 64 * sizeof(uint2);                 // 2 MB
  const size_t slab_bytes = (size_t)(NB / BTILE) * SLAB_DW * sizeof(uint32_t); // 8 MB
  const int grid = (NB / BTILE) * OSPLIT;                                      // 512

  if (ws_size >= pack_bytes + slab_bytes) {
    uint2*    pack2 = (uint2*)d_ws;
    uint32_t* slab  = (uint32_t*)((char*)d_ws + pack_bytes);
    prep_kernel<<<SLAB_BLOCKS + SORT_BLOCKS, 256, 0, stream>>>(input, slab, idxs, weight, pack2);
    lincond_kernel<<<grid, 1024, 0, stream>>>(slab, pack2, bias, out);
  } else {
    lincond_raw<<<(NB * NOUT) / 256, 256, 0, stream>>>(input, weight, bias, idxs, out);
  }
}

// Round 15
// 51.783 us; speedup vs baseline: 2.5987x; 1.0224x over previous
//
#include <hip/hip_runtime.h>
#include <hip/hip_fp16.h>
#include <stdint.h>

#define NB    1024
#define IL    4096
#define NOUT  4096
#define FI    128
#define BTILE 8
#define OSPLIT 4
#define OTILE (NOUT / OSPLIT)        // 1024 outputs per block
#define SLAB_DW (IL * (BTILE / 2))   // 16384 dwords = 64KB per batch-group slab
#define SLAB_BLOCKS ((NB / BTILE) * IL / 256)   // 2048
#define SORT_BLOCKS (NOUT / 4)                  // 1024 (wave per row)

typedef _Float16 h2v __attribute__((ext_vector_type(2)));
__device__ __forceinline__ h2v as_h2(uint32_t u){ union{uint32_t u; h2v h;} c; c.u=u; return c.h; }
#if __has_builtin(__builtin_amdgcn_fdot2)
__device__ __forceinline__ float fdot2(h2v a, h2v b, float c){ return __builtin_amdgcn_fdot2(a,b,c,false); }
#else
__device__ __forceinline__ float fdot2(h2v a, h2v b, float c){ return c + (float)a[0]*(float)b[0] + (float)a[1]*(float)b[1]; }
#endif

__device__ __forceinline__ uint32_t f16bits(float x) {
  return (uint32_t)__half_as_ushort(__float2half(x));   // RNE f32->f16
}

// ---------------- merged pre-pass (one launch, unchanged from R14) ----------------
__global__ __launch_bounds__(256)
void prep_kernel(const float* __restrict__ in, uint32_t* __restrict__ slab,
                 const int* __restrict__ idx, const float* __restrict__ w,
                 uint2* __restrict__ pack2) {
  __shared__ uint32_t sbuf[4][FI];
  const int bid = blockIdx.x;
  if (bid < SLAB_BLOCKS) {
    int t = bid * 256 + threadIdx.x;
    int g = t >> 12;
    int i = t & (IL - 1);
    const float* base = in + (size_t)g * (8 * IL) + i;
    uint4 v;
    v.x = (f16bits(base[1 * IL]) << 16) | f16bits(base[0 * IL]);
    v.y = (f16bits(base[3 * IL]) << 16) | f16bits(base[2 * IL]);
    v.z = (f16bits(base[5 * IL]) << 16) | f16bits(base[4 * IL]);
    v.w = (f16bits(base[7 * IL]) << 16) | f16bits(base[6 * IL]);
    reinterpret_cast<uint4*>(slab)[t] = v;
  } else {
    const int wv = threadIdx.x >> 6;
    const int o = (bid - SLAB_BLOCKS) * 4 + wv;
    const unsigned lane = threadIdx.x & 63u;
    const uint32_t r = (uint32_t)(o & 7);
    const int*   irow = idx + (size_t)o * FI;
    const float* wrow = w   + (size_t)o * FI;

    uint32_t i0 = (uint32_t)irow[lane], i1 = (uint32_t)irow[64 + lane];
    uint32_t e0 = (f16bits(wrow[lane])      << 16) | ((i0 << 4) & 0xFFFFu);
    uint32_t e1 = (f16bits(wrow[64 + lane]) << 16) | ((i1 << 4) & 0xFFFFu);
    uint32_t k0 = i0 & 7u, k1 = i1 & 7u;
    const uint64_t lt = (1ull << lane) - 1ull;

    uint32_t rank0 = 0, rank1 = 0;
    uint64_t cntp = 0;
    #pragma unroll
    for (int g = 0; g < 8; ++g) {
      uint64_t b0 = __ballot(k0 == (uint32_t)g);
      uint64_t b1 = __ballot(k1 == (uint32_t)g);
      uint32_t c0 = (uint32_t)__popcll(b0);
      if (k0 == (uint32_t)g) rank0 = (uint32_t)__popcll(b0 & lt);
      if (k1 == (uint32_t)g) rank1 = c0 + (uint32_t)__popcll(b1 & lt);
      cntp |= (uint64_t)(c0 + (uint32_t)__popcll(b1)) << (8 * g);
    }
    uint64_t ov0 = __ballot(rank0 >= 16u);
    uint64_t ov1 = __ballot(rank1 >= 16u);
    uint32_t ofr0 = (uint32_t)__popcll(ov0 & lt);
    uint32_t ofr1 = (uint32_t)__popcll(ov0) + (uint32_t)__popcll(ov1 & lt);

    auto place = [&](uint32_t k, uint32_t rank, uint32_t ofr) -> uint32_t {
      if (rank < 16u) return ((k - r) & 7u) + 8u * rank;
      uint32_t cum = 0, p = 0;
      bool done = false;
      #pragma unroll
      for (int lc = 0; lc < 8; ++lc) {
        uint32_t gl = ((uint32_t)lc + r) & 7u;
        uint32_t c  = (uint32_t)((cntp >> (8 * gl)) & 0xFFu);
        uint32_t u  = c < 16u ? c : 16u;
        uint32_t lcnt = 16u - u;
        if (!done && ofr < cum + lcnt) { p = (uint32_t)lc + 8u * (u + ofr - cum); done = true; }
        cum += lcnt;
      }
      return p;
    };
    sbuf[wv][place(k0, rank0, ofr0)] = e0;
    sbuf[wv][place(k1, rank1, ofr1)] = e1;
    __syncthreads();   // uniform branch within block: safe

    uint32_t s0 = sbuf[wv][2 * lane], s1 = sbuf[wv][2 * lane + 1];
    uint2 pe;
    pe.x = ((s0 & 0xFFFFu) << 16) | (s1 & 0xFFFFu);        // addr(f1) hi | addr(f2) lo
    pe.y = (s1 & 0xFFFF0000u) | (s0 >> 16);                // w2 hi | w1 lo
    pack2[(size_t)o * 64 + lane] = pe;
  }
}

// shared staging: linear 64KB DMA global->LDS
__device__ __forceinline__ void stage_slab(const uint32_t* src, uint32_t* lds, int tid) {
  #pragma unroll
  for (int r = 0; r < 4; ++r) {
    int e = (r * 1024 + tid) * 4;
    __builtin_amdgcn_global_load_lds(
        (const __attribute__((address_space(1))) uint32_t*)(src + e),
        (__attribute__((address_space(3))) uint32_t*)(lds + e),
        16, 0, 0);
  }
}

// main kernel: DMA staging + software-pipelined paired-gather dot2 loop.
// Per j: batch 4 pack loads (asm keep-alive -> one vmcnt wait), then alternate
// two gather-quads so the next pair's 2 ds_read_b128 are issued before the
// previous pair's 16 perm+dot2 consume -> ds latency hidden under VALU.
__global__ __launch_bounds__(1024)
void lincond_kernel(const uint32_t* __restrict__ slab,
                    const uint2* __restrict__ pack2,
                    const float* __restrict__ bias,
                    float* __restrict__ out) {
  __shared__ uint32_t lds[SLAB_DW];
  const int bid   = blockIdx.x;
  const int b0    = (bid >> 2) * BTILE;
  const int obase = (bid & 3) * OTILE;
  const int tid   = threadIdx.x;
  stage_slab(slab + (size_t)(b0 >> 3) * SLAB_DW, lds, tid);
  __syncthreads();

  const int o = obase + tid;
  const char* ldsb = reinterpret_cast<const char*>(lds);
  float acc[8] = {0.f,0.f,0.f,0.f,0.f,0.f,0.f,0.f};
  const uint4* pw4 = reinterpret_cast<const uint4*>(pack2) + (size_t)o * 32;

#define KEEP4(P) asm volatile("" :: "v"((P).x), "v"((P).y), "v"((P).z), "v"((P).w))

// issue the 2 ds_read_b128 of one pair-entry (addr word AD) into G1,G2
#define RD2(AD, G1, G2) {                                                       \
    uint32_t a1_ = (AD) >> 16, a2_ = (AD) & 0xFFFFu;                            \
    G1 = *reinterpret_cast<const uint4*>(ldsb + a1_);                           \
    G2 = *reinterpret_cast<const uint4*>(ldsb + a2_); }

#define DOT2P(U1, U2, WT, K0, K1) {                                             \
    acc[K0] = fdot2(as_h2(__builtin_amdgcn_perm((U2), (U1), 0x05040100u)),      \
                    as_h2(WT), acc[K0]);                                        \
    acc[K1] = fdot2(as_h2(__builtin_amdgcn_perm((U2), (U1), 0x07060302u)),      \
                    as_h2(WT), acc[K1]);}

// consume one pair-entry: rows G1 (f1), G2 (f2), packed weights WT
#define CONS(G1, G2, WT) {                                                      \
    DOT2P((G1).x, (G2).x, WT, 0, 1)                                             \
    DOT2P((G1).y, (G2).y, WT, 2, 3)                                             \
    DOT2P((G1).z, (G2).z, WT, 4, 5)                                             \
    DOT2P((G1).w, (G2).w, WT, 6, 7)}

  #pragma unroll 1
  for (int j = 0; j < 8; ++j) {
    uint4 p0 = pw4[j * 4 + 0];
    uint4 p1 = pw4[j * 4 + 1];
    uint4 p2 = pw4[j * 4 + 2];
    uint4 p3 = pw4[j * 4 + 3];
    KEEP4(p0); KEEP4(p1); KEEP4(p2); KEEP4(p3);   // 4 loads batched, one wait

    uint4 ga1, ga2, gb1, gb2;
    RD2(p0.x, ga1, ga2);                    // prologue: pair 0 in flight
    RD2(p0.z, gb1, gb2);  CONS(ga1, ga2, p0.y);
    RD2(p1.x, ga1, ga2);  CONS(gb1, gb2, p0.w);
    RD2(p1.z, gb1, gb2);  CONS(ga1, ga2, p1.y);
    RD2(p2.x, ga1, ga2);  CONS(gb1, gb2, p1.w);
    RD2(p2.z, gb1, gb2);  CONS(ga1, ga2, p2.y);
    RD2(p3.x, ga1, ga2);  CONS(gb1, gb2, p2.w);
    RD2(p3.z, gb1, gb2);  CONS(ga1, ga2, p3.y);
                          CONS(gb1, gb2, p3.w);   // epilogue
  }

  const float bv = bias[o];
  #pragma unroll
  for (int k = 0; k < 8; ++k)
    out[(size_t)(b0 + k) * NOUT + o] = acc[k] + bv;
}

// fallback (no workspace): naive but correct
__global__ __launch_bounds__(256)
void lincond_raw(const float* __restrict__ input, const float* __restrict__ wgt,
                 const float* __restrict__ bias, const int* __restrict__ idxs,
                 float* __restrict__ out) {
  int t = blockIdx.x * 256 + threadIdx.x;
  int b = t >> 12, o = t & (NOUT - 1);
  const float* irow = input + (size_t)b * IL;
  const int*   ix   = idxs + (size_t)o * FI;
  const float* wr   = wgt  + (size_t)o * FI;
  float acc = bias[o];
  for (int f = 0; f < FI; ++f) acc += wr[f] * irow[ix[f]];
  out[t] = acc;
}

extern "C" void kernel_launch(void* const* d_in, const int* in_sizes, int n_in,
                              void* d_out, int out_size, void* d_ws, size_t ws_size,
                              hipStream_t stream) {
  const float* input  = (const float*)d_in[0];
  const float* weight = (const float*)d_in[1];
  const float* bias   = (const float*)d_in[2];
  const int*   idxs   = (const int*)d_in[3];
  float*       out    = (float*)d_out;

  const size_t pack_bytes = (size_t)NOUT * 64 * sizeof(uint2);                 // 2 MB
  const size_t slab_bytes = (size_t)(NB / BTILE) * SLAB_DW * sizeof(uint32_t); // 8 MB
  const int grid = (NB / BTILE) * OSPLIT;                                      // 512

  if (ws_size >= pack_bytes + slab_bytes) {
    uint2*    pack2 = (uint2*)d_ws;
    uint32_t* slab  = (uint32_t*)((char*)d_ws + pack_bytes);
    prep_kernel<<<SLAB_BLOCKS + SORT_BLOCKS, 256, 0, stream>>>(input, slab, idxs, weight, pack2);
    lincond_kernel<<<grid, 1024, 0, stream>>>(slab, pack2, bias, out);
  } else {
    lincond_raw<<<(NB * NOUT) / 256, 256, 0, stream>>>(input, weight, bias, idxs, out);
  }
}